// Round 17
// baseline (109.679 us; speedup 1.0000x reference)
//
#include <hip/hip_runtime.h>

// NVFP4 (e2m1 + e4m3 block scale) quantize-dequantize, block=16 contiguous.
// Memory-bound: 256 MiB in + 256 MiB out. PASSED R14/R15 with absmax 0.0.
//
// Reference semantics (solved rounds 1-13, verified R14/R15) — DO NOT TOUCH:
//  - SCALE ("A2"): s = e4m3_RNE( amax * fl32(scaling_factor/6) ), all f32.
//  - QUOTIENT: y = x * fl32(1/scale_safe)  (reciprocal-multiply; the f32
//    IEEE divide for the reciprocal is mandatory - rcp approx would break).
//  - BINNING: searchsorted(mids, |y|, side='right') == inclusive >= against
//    literal mids; clip at 6 subsumed by the >=5 threshold.
//  - OUTPUT: copysign(g*s, x); g*s exact (<=9 sig bits).
//
// R17 = R16 with the DPP ctrl as a template (immediate) parameter:
//  - DPP quad-perm max replaces __shfl_xor (ds_swizzle): the 4-lane block
//    amax reduce becomes 4 VALU ops, removing LDS round-trips + lgkmcnt
//    waits from every tile's dependent chain.
//  - Explicit prefetch of the next grid-stride iteration's 4 loads before
//    computing the current one: next-iter HBM latency hides under compute.

typedef float f4 __attribute__((ext_vector_type(4)));

template <int CTRL>
__device__ __forceinline__ float quad_xor_max(float x) {
    int xi = __float_as_int(x);
    int yi = __builtin_amdgcn_update_dpp(xi, xi, CTRL, 0xF, 0xF, true);
    return fmaxf(x, __int_as_float(yi));
}

__device__ __forceinline__ float e4m3_scale(float amax, float rsix) {
    float a = amax * rsix;                // A2: single f32 multiply
    a = fminf(a, 448.0f);
    if (a == 0.0f) return 0.0f;
    unsigned bits = __float_as_uint(a);
    int e = (int)((bits >> 23) & 0xFFu) - 127;  // floor(log2(a)) for normals
    e = e < -6 ? -6 : (e > 8 ? 8 : e);
    float quantum = __uint_as_float((unsigned)((e - 3) + 127) << 23); // 2^(e-3)
    float inv_q   = __uint_as_float((unsigned)((3 - e) + 127) << 23); // 2^(3-e)
    return rintf(a * inv_q) * quantum;    // exact pow2 scaling + RNE (np.round)
}

__device__ __forceinline__ float fp4_one(float xv, float r, float s) {
    float y = xv * r;                     // reciprocal-multiply, f32 RNE
    float a = fabsf(y);
    float g = (a >= 0.25f) ? 0.5f : 0.0f; // searchsorted 'right': ties up
    g += (a >= 0.75f) ? 0.5f : 0.0f;      // grid: 0,.5,1,1.5,2,3,4,6
    g += (a >= 1.25f) ? 0.5f : 0.0f;
    g += (a >= 1.75f) ? 0.5f : 0.0f;
    g += (a >= 2.5f)  ? 1.0f : 0.0f;
    g += (a >= 3.5f)  ? 1.0f : 0.0f;
    g += (a >= 5.0f)  ? 2.0f : 0.0f;      // >=5 -> 6 (clip subsumed)
    return copysignf(g * s, xv);          // exact product (<=9 sig bits)
}

__device__ __forceinline__ f4 tile_q(f4 v, float rsix) {
    float amax = fmaxf(fmaxf(fabsf(v[0]), fabsf(v[1])),
                       fmaxf(fabsf(v[2]), fabsf(v[3])));
    amax = quad_xor_max<0xB1>(amax);      // quad_perm [1,0,3,2] (xor-1)
    amax = quad_xor_max<0x4E>(amax);      // quad_perm [2,3,0,1] (xor-2)
    const float s = e4m3_scale(amax, rsix);
    const float ssafe = (s == 0.0f) ? 1.0f : s;
    const float r = 1.0f / ssafe;         // IEEE f32 divide (required)
    f4 o;
    o[0] = fp4_one(v[0], r, s);
    o[1] = fp4_one(v[1], r, s);
    o[2] = fp4_one(v[2], r, s);
    o[3] = fp4_one(v[3], r, s);
    return o;
}

__global__ __launch_bounds__(256) void nvfp4_qdq_kernel(
    const f4* __restrict__ x4, const float* __restrict__ sfp,
    f4* __restrict__ o4, int q) {           // q = n4/4 float4s per quarter
    const float rsix = sfp[0] / 6.0f;       // fl32(sf/6), hoisted scalar (A2)
    const int stride = gridDim.x * blockDim.x;
    int i = blockIdx.x * blockDim.x + threadIdx.x;
    if (i >= q) return;
    // Current iteration's 4 independent quarter-loads (64B/lane in flight).
    f4 c0 = __builtin_nontemporal_load(x4 + i);
    f4 c1 = __builtin_nontemporal_load(x4 + i + q);
    f4 c2 = __builtin_nontemporal_load(x4 + i + 2 * (size_t)q);
    f4 c3 = __builtin_nontemporal_load(x4 + i + 3 * (size_t)q);
    for (;;) {
        const int nx = i + stride;
        const bool has = nx < q;            // uniform (q % stride == 0)
        f4 n0, n1, n2, n3;
        if (has) {                          // prefetch next iteration early
            n0 = __builtin_nontemporal_load(x4 + nx);
            n1 = __builtin_nontemporal_load(x4 + nx + q);
            n2 = __builtin_nontemporal_load(x4 + nx + 2 * (size_t)q);
            n3 = __builtin_nontemporal_load(x4 + nx + 3 * (size_t)q);
        }
        f4 r0 = tile_q(c0, rsix);
        f4 r1 = tile_q(c1, rsix);
        f4 r2 = tile_q(c2, rsix);
        f4 r3 = tile_q(c3, rsix);
        __builtin_nontemporal_store(r0, o4 + i);
        __builtin_nontemporal_store(r1, o4 + i + q);
        __builtin_nontemporal_store(r2, o4 + i + 2 * (size_t)q);
        __builtin_nontemporal_store(r3, o4 + i + 3 * (size_t)q);
        if (!has) break;
        i = nx; c0 = n0; c1 = n1; c2 = n2; c3 = n3;
    }
}

extern "C" void kernel_launch(void* const* d_in, const int* in_sizes, int n_in,
                              void* d_out, int out_size, void* d_ws, size_t ws_size,
                              hipStream_t stream) {
    const f4* x = (const f4*)d_in[0];
    const float* sf = (const float*)d_in[1];
    f4* out = (f4*)d_out;
    int n4 = out_size / 4;   // 16,777,216 float4s for 8192x8192
    int q = n4 / 4;          // quarter size in float4s (multiple of 4)
    int block = 256;
    int maxBlocks = 2048;    // 8 wg/CU; q % (2048*256) == 0 -> uniform trips
    int grid = (q + block - 1) / block;
    if (grid > maxBlocks) grid = maxBlocks;
    nvfp4_qdq_kernel<<<grid, block, 0, stream>>>(x, sf, out, q);
}

// Round 18
// 93.285 us; speedup vs baseline: 1.1757x; 1.1757x over previous
//
#include <hip/hip_runtime.h>

// NVFP4 (e2m1 + e4m3 block scale) quantize-dequantize, block=16 contiguous.
// Memory-bound: 256 MiB in + 256 MiB out. PASSED R14/R15/R17 with absmax 0.0.
//
// Reference semantics (solved rounds 1-13, verified R14/R15/R17) — DO NOT TOUCH:
//  - SCALE ("A2"): s = e4m3_RNE( amax * fl32(scaling_factor/6) ), all f32.
//  - QUOTIENT: y = x * fl32(1/scale_safe)  (reciprocal-multiply; the f32
//    IEEE divide for the reciprocal is mandatory - rcp approx would break).
//  - BINNING: searchsorted(mids, |y|, side='right') == inclusive >= against
//    literal mids; clip at 6 subsumed by the >=5 threshold.
//  - OUTPUT: copysign(g*s, x); g*s exact (<=9 sig bits).
//
// R18 = R15 structure (best measured: 104.3us) + two minimal deltas:
//  - __shfl_xor -> DPP quad-perm max (template-immediate ctrl): pure-VALU
//    4-lane reduce, no LDS round-trip / lgkmcnt in the dependent chain.
//    (R17's regression is attributed to its prefetch-rotate structure,
//    +16 live VGPRs — reverted.)
//  - Stores drop the nontemporal hint: output (256 MiB) == Infinity Cache
//    capacity; allowing L3 write-allocate lets stores retire at L3 speed
//    and drain past the kernel. Loads stay NT so the input stream doesn't
//    evict pending write lines. Diagnostic: FETCH_SIZE ~262MB good;
//    ~520MB = write-RFO -> revert.

typedef float f4 __attribute__((ext_vector_type(4)));

template <int CTRL>
__device__ __forceinline__ float quad_xor_max(float x) {
    int xi = __float_as_int(x);
    int yi = __builtin_amdgcn_update_dpp(xi, xi, CTRL, 0xF, 0xF, true);
    return fmaxf(x, __int_as_float(yi));
}

__device__ __forceinline__ float e4m3_scale(float amax, float rsix) {
    float a = amax * rsix;                // A2: single f32 multiply
    a = fminf(a, 448.0f);
    if (a == 0.0f) return 0.0f;
    unsigned bits = __float_as_uint(a);
    int e = (int)((bits >> 23) & 0xFFu) - 127;  // floor(log2(a)) for normals
    e = e < -6 ? -6 : (e > 8 ? 8 : e);
    float quantum = __uint_as_float((unsigned)((e - 3) + 127) << 23); // 2^(e-3)
    float inv_q   = __uint_as_float((unsigned)((3 - e) + 127) << 23); // 2^(3-e)
    return rintf(a * inv_q) * quantum;    // exact pow2 scaling + RNE (np.round)
}

__device__ __forceinline__ float fp4_one(float xv, float r, float s) {
    float y = xv * r;                     // reciprocal-multiply, f32 RNE
    float a = fabsf(y);
    float g = (a >= 0.25f) ? 0.5f : 0.0f; // searchsorted 'right': ties up
    g += (a >= 0.75f) ? 0.5f : 0.0f;      // grid: 0,.5,1,1.5,2,3,4,6
    g += (a >= 1.25f) ? 0.5f : 0.0f;
    g += (a >= 1.75f) ? 0.5f : 0.0f;
    g += (a >= 2.5f)  ? 1.0f : 0.0f;
    g += (a >= 3.5f)  ? 1.0f : 0.0f;
    g += (a >= 5.0f)  ? 2.0f : 0.0f;      // >=5 -> 6 (clip subsumed)
    return copysignf(g * s, xv);          // exact product (<=9 sig bits)
}

__device__ __forceinline__ f4 tile_q(f4 v, float rsix) {
    float amax = fmaxf(fmaxf(fabsf(v[0]), fabsf(v[1])),
                       fmaxf(fabsf(v[2]), fabsf(v[3])));
    amax = quad_xor_max<0xB1>(amax);      // quad_perm [1,0,3,2] (xor-1)
    amax = quad_xor_max<0x4E>(amax);      // quad_perm [2,3,0,1] (xor-2)
    const float s = e4m3_scale(amax, rsix);
    const float ssafe = (s == 0.0f) ? 1.0f : s;
    const float r = 1.0f / ssafe;         // IEEE f32 divide (required)
    f4 o;
    o[0] = fp4_one(v[0], r, s);
    o[1] = fp4_one(v[1], r, s);
    o[2] = fp4_one(v[2], r, s);
    o[3] = fp4_one(v[3], r, s);
    return o;
}

__global__ __launch_bounds__(256) void nvfp4_qdq_kernel(
    const f4* __restrict__ x4, const float* __restrict__ sfp,
    f4* __restrict__ o4, int q) {           // q = n4/4 float4s per quarter
    const float rsix = sfp[0] / 6.0f;       // fl32(sf/6), hoisted scalar (A2)
    const int stride = gridDim.x * blockDim.x;
    for (int i = blockIdx.x * blockDim.x + threadIdx.x; i < q; i += stride) {
        // 4 independent quarter-loads (64B/lane in flight), NT (read-once).
        f4 v0 = __builtin_nontemporal_load(x4 + i);
        f4 v1 = __builtin_nontemporal_load(x4 + i + q);
        f4 v2 = __builtin_nontemporal_load(x4 + i + 2 * (size_t)q);
        f4 v3 = __builtin_nontemporal_load(x4 + i + 3 * (size_t)q);
        f4 r0 = tile_q(v0, rsix);
        f4 r1 = tile_q(v1, rsix);
        f4 r2 = tile_q(v2, rsix);
        f4 r3 = tile_q(v3, rsix);
        o4[i]                   = r0;       // plain stores: L3 write-absorb
        o4[i + q]               = r1;
        o4[i + 2 * (size_t)q]   = r2;
        o4[i + 3 * (size_t)q]   = r3;
    }
}

extern "C" void kernel_launch(void* const* d_in, const int* in_sizes, int n_in,
                              void* d_out, int out_size, void* d_ws, size_t ws_size,
                              hipStream_t stream) {
    const f4* x = (const f4*)d_in[0];
    const float* sf = (const float*)d_in[1];
    f4* out = (f4*)d_out;
    int n4 = out_size / 4;   // 16,777,216 float4s for 8192x8192
    int q = n4 / 4;          // quarter size in float4s (multiple of 4)
    int block = 256;
    int maxBlocks = 2048;    // 8 wg/CU; grid-stride covers the rest
    int grid = (q + block - 1) / block;
    if (grid > maxBlocks) grid = maxBlocks;
    nvfp4_qdq_kernel<<<grid, block, 0, stream>>>(x, sf, out, q);
}